// Round 4
// baseline (1822.197 us; speedup 1.0000x reference)
//
#include <hip/hip_runtime.h>

#define T_LEN 2048
#define HID 64
#define NG 256     // 4*HID gate rows per layer
#define EMB 128
#define NITER (T_LEN + 4)

typedef _Float16 half2_t __attribute__((ext_vector_type(2)));

// v_dot2_f32_f16: 2-way f16 dot, f32 accumulate.
__device__ __forceinline__ float fdot2(uint32_t a, uint32_t b, float c) {
    return __builtin_amdgcn_fdot2(__builtin_bit_cast(half2_t, a),
                                  __builtin_bit_cast(half2_t, b), c, false);
}

// Load 64 f16 (128 B) from LDS as 8x uint4 (ds_read_b128, same-addr broadcast).
__device__ __forceinline__ void load_h(const _Float16* hbase, uint32_t* u) {
    const uint4* p = reinterpret_cast<const uint4*>(hbase);
    #pragma unroll
    for (int k = 0; k < 8; ++k) {
        uint4 v = p[k];
        u[4 * k + 0] = v.x; u[4 * k + 1] = v.y;
        u[4 * k + 2] = v.z; u[4 * k + 3] = v.w;
    }
}

__device__ __forceinline__ float dot64(const uint32_t* w, const uint32_t* h, float acc) {
    #pragma unroll
    for (int k = 0; k < 32; ++k) acc = fdot2(w[k], h[k], acc);
    return acc;
}

// One 64-float weight row -> 32 packed f16 pairs in VGPRs.
__device__ __forceinline__ void cvt_row(const float* __restrict__ W, int row, uint32_t* dst) {
    const float4* W4 = reinterpret_cast<const float4*>(W + row * HID);
    #pragma unroll
    for (int k = 0; k < 16; ++k) {
        float4 v = W4[k];
        half2_t a{(_Float16)v.x, (_Float16)v.y};
        half2_t b{(_Float16)v.z, (_Float16)v.w};
        dst[2 * k]     = __builtin_bit_cast(uint32_t, a);
        dst[2 * k + 1] = __builtin_bit_cast(uint32_t, b);
    }
}

// One block per batch element; 768 threads = 3 stages x 4 waves.
// Lane map: wave w of a stage owns h-indices [16w,16w+16); lane = cls*16+iloc
// computes gate row (cls*64 + 16w + iloc). The 4 gates of one h-index sit in
// lanes {iloc, 16+iloc, 32+iloc, 48+iloc} of ONE wave -> gate exchange is
// three __shfl_xor, cell update is wave-local => ONE barrier per iteration
// (R3 had two; barrier drain was ~half the iteration).
// 5-task wavefront pipeline (unchanged from R3):
//   S0: gates0->h0[s]; p1[s-1]=Wih1.h0[s-1]
//   S1: gates1->h1[s-2] (uses p1[s-2]); p2[s-3]=Wih2.h1[s-3]
//   S2: gates2->h2[s-4] (uses p2[s-4])
// All cross-task edges are written@s-1/read@s -> single end-of-iter barrier.
// x is staged to LDS up front so the loop has NO global ops (no vmcnt drain
// at the barrier). Weights/h are packed f16 (uint32 half2), accum f32.
__global__ __launch_bounds__(768, 3) void lstm3_fused(
    const float* __restrict__ x,
    const float* __restrict__ Wih0, const float* __restrict__ Whh0,
    const float* __restrict__ bih0, const float* __restrict__ bhh0,
    const float* __restrict__ Wih1, const float* __restrict__ Whh1,
    const float* __restrict__ bih1, const float* __restrict__ bhh1,
    const float* __restrict__ Wih2, const float* __restrict__ Whh2,
    const float* __restrict__ bih2, const float* __restrict__ bhh2,
    const float* __restrict__ fcW,  const float* __restrict__ fcb,
    float* __restrict__ out)
{
    const int b     = blockIdx.x;
    const int tid   = threadIdx.x;
    const int stage = tid >> 8;        // 0,1,2
    const int lane  = tid & 63;
    const int wv    = (tid >> 6) & 3;  // wave within stage
    const int iloc  = lane & 15;
    const int cls   = lane >> 4;       // 0=i,1=f,2=g,3=o
    const int hidx  = wv * 16 + iloc;  // h index [0,64)
    const int row   = cls * HID + hidx;// gate row [0,256)

    __shared__ __align__(16) _Float16 h0f[2][HID];
    __shared__ __align__(16) _Float16 h1f[2][HID];
    __shared__ __align__(16) _Float16 h2f[2][HID];
    __shared__ float p1buf[2][NG], p2buf[2][NG];
    __shared__ float hfin[HID];
    __shared__ __align__(16) float xs[T_LEN];

    // Stage x[b,0,:] into LDS (coalesced float4; 512 float4).
    {
        const float4* xg4 = reinterpret_cast<const float4*>(x + b * T_LEN);
        float4* xs4 = reinterpret_cast<float4*>(xs);
        if (tid < T_LEN / 4) xs4[tid] = xg4[tid];
        if (tid + 768 < T_LEN / 4) { }  // T_LEN/4 = 512 < 768: single pass
    }
    if (tid < HID) {
        h0f[0][tid] = (_Float16)0.f; h0f[1][tid] = (_Float16)0.f;
        h1f[0][tid] = (_Float16)0.f; h1f[1][tid] = (_Float16)0.f;
        h2f[0][tid] = (_Float16)0.f; h2f[1][tid] = (_Float16)0.f;
    }

    uint32_t wh[32], wi[32];           // 64 VGPRs of packed f16 weights
    float wx0 = 0.f, bj = 0.f;
    if (stage == 0) {
        wx0 = Wih0[row];               // Wih0 is [256,1]
        bj  = bih0[row] + bhh0[row];
        cvt_row(Whh0, row, wh);
        cvt_row(Wih1, row, wi);        // p1 task
    } else if (stage == 1) {
        bj = bih1[row] + bhh1[row];
        cvt_row(Whh1, row, wh);
        cvt_row(Wih2, row, wi);        // p2 task
    } else {
        bj = bih2[row] + bhh2[row];
        cvt_row(Whh2, row, wh);
        #pragma unroll
        for (int k = 0; k < 32; ++k) wi[k] = 0;
    }

    // Per-lane branchless activation constants: gate class 2 -> tanh,
    // else sigmoid. act(x) = sA * 1/(1+exp(sN*x)) + sB.
    const bool  isg = (cls == 2);
    const float sN  = isg ? -2.f : -1.f;
    const float sA  = isg ?  2.f :  1.f;
    const float sB  = isg ? -1.f :  0.f;

    float c = 0.f;                     // cell state (lives in cls==0 lanes)
    __syncthreads();

    for (int s = 0; s < NITER; ++s) {
        const int rd = (s + 1) & 1;    // slot written at iter s-1
        const int wr = s & 1;

        bool act;
        float acc;
        uint32_t hv[32];
        if (stage == 0) {
            act = (s < T_LEN);
            load_h(h0f[rd], hv);                    // h0[s-1]
            acc = fmaf(wx0, xs[act ? s : 0], bj);
            acc = dot64(wh, hv, acc);               // whh0 . h0[s-1]
            if (s >= 1 && s <= T_LEN)
                p1buf[wr][row] = dot64(wi, hv, 0.f);  // Wih1 . h0[s-1]
        } else if (stage == 1) {
            act = (s >= 2 && s <= T_LEN + 1);
            load_h(h1f[rd], hv);                    // h1[s-3]
            acc = bj + p1buf[rd][row];              // p1[s-2]
            acc = dot64(wh, hv, acc);
            if (s >= 3 && s <= T_LEN + 2)
                p2buf[wr][row] = dot64(wi, hv, 0.f);  // Wih2 . h1[s-3]
        } else {
            act = (s >= 4);
            load_h(h2f[rd], hv);                    // h2[s-5]
            acc = bj + p2buf[rd][row];              // p2[s-4]
            acc = dot64(wh, hv, acc);
        }

        // Own gate activation (all lanes, branchless).
        float e = __expf(sN * acc);
        float a = fmaf(sA, 1.f / (1.f + e), sB);

        // Gather the 4 gate classes of this h-index (all in this wave).
        float t1 = __shfl_xor(a, 16, 64);   // cls^1
        float t2 = __shfl_xor(a, 32, 64);   // cls^2
        float t3 = __shfl_xor(t1, 32, 64);  // cls^3

        if (cls == 0 && act) {
            // For cls==0: (i,f,g,o) = (a, t1, t2, t3).
            c = fmaf(t1, c, a * t2);
            float tc = 2.f / (1.f + __expf(-2.f * c)) - 1.f;
            float h  = t3 * tc;
            _Float16* ring = (stage == 0) ? h0f[wr] : (stage == 1) ? h1f[wr] : h2f[wr];
            ring[hidx] = (_Float16)h;
            if (stage == 2 && s == NITER - 1) hfin[hidx] = h;  // h2[T-1]
        }
        __syncthreads();   // ring + p-buffer writes visible for iter s+1
    }

    // Final FC (f32): out[b,m] = fcb[m] + fcW[m,:] . h2_last
    if (tid < EMB) {
        float acc = fcb[tid];
        const float4* W4 = reinterpret_cast<const float4*>(fcW + tid * HID);
        const float4* h4 = reinterpret_cast<const float4*>(hfin);
        #pragma unroll
        for (int k = 0; k < 16; ++k) {
            float4 wv4 = W4[k], hv4 = h4[k];
            acc = fmaf(wv4.x, hv4.x, acc);
            acc = fmaf(wv4.y, hv4.y, acc);
            acc = fmaf(wv4.z, hv4.z, acc);
            acc = fmaf(wv4.w, hv4.w, acc);
        }
        out[b * EMB + tid] = acc;
    }
}

extern "C" void kernel_launch(void* const* d_in, const int* in_sizes, int n_in,
                              void* d_out, int out_size, void* d_ws, size_t ws_size,
                              hipStream_t stream) {
    const float* x    = (const float*)d_in[0];
    const float* Wih0 = (const float*)d_in[1];
    const float* Whh0 = (const float*)d_in[2];
    const float* bih0 = (const float*)d_in[3];
    const float* bhh0 = (const float*)d_in[4];
    const float* Wih1 = (const float*)d_in[5];
    const float* Whh1 = (const float*)d_in[6];
    const float* bih1 = (const float*)d_in[7];
    const float* bhh1 = (const float*)d_in[8];
    const float* Wih2 = (const float*)d_in[9];
    const float* Whh2 = (const float*)d_in[10];
    const float* bih2 = (const float*)d_in[11];
    const float* bhh2 = (const float*)d_in[12];
    const float* fcW  = (const float*)d_in[13];
    const float* fcb  = (const float*)d_in[14];
    float* out = (float*)d_out;

    lstm3_fused<<<dim3(256), dim3(768), 0, stream>>>(
        x, Wih0, Whh0, bih0, bhh0,
        Wih1, Whh1, bih1, bhh1,
        Wih2, Whh2, bih2, bhh2,
        fcW, fcb, out);
}

// Round 5
// 1473.671 us; speedup vs baseline: 1.2365x; 1.2365x over previous
//
#include <hip/hip_runtime.h>

#define T_LEN 2048
#define HID 64
#define NG 256     // 4*HID gate rows per layer
#define EMB 128
#define NITER (T_LEN + 4)

typedef _Float16 half2_t __attribute__((ext_vector_type(2)));

#if __has_builtin(__builtin_amdgcn_exp2f)
#define EXP2F(x) __builtin_amdgcn_exp2f(x)
#else
#define EXP2F(x) exp2f(x)
#endif
#if __has_builtin(__builtin_amdgcn_rcpf)
#define RCPF(x) __builtin_amdgcn_rcpf(x)
#else
#define RCPF(x) (1.0f / (x))
#endif

#define LOG2E 1.4426950408889634f

// v_dot2_f32_f16: 2-way f16 dot, f32 accumulate.
__device__ __forceinline__ float fdot2(uint32_t a, uint32_t b, float c) {
    return __builtin_amdgcn_fdot2(__builtin_bit_cast(half2_t, a),
                                  __builtin_bit_cast(half2_t, b), c, false);
}

// Quad-broadcast via DPP quad_perm (VALU pipe, ~4 cyc — NOT ds_permute;
// R4's __shfl_xor = 2 serial LDS-pipe ops ~200 cyc, the R4 regression).
template <int CTRL>
__device__ __forceinline__ float qbcast(float v) {
    int r = __builtin_amdgcn_update_dpp(0, __builtin_bit_cast(int, v),
                                        CTRL, 0xF, 0xF, true);
    return __builtin_bit_cast(float, r);
}

// Load 64 f16 (128 B) from LDS as 8x uint4 (ds_read_b128, same-addr broadcast).
__device__ __forceinline__ void load_h(const _Float16* hbase, uint32_t* u) {
    const uint4* p = reinterpret_cast<const uint4*>(hbase);
    #pragma unroll
    for (int k = 0; k < 8; ++k) {
        uint4 v = p[k];
        u[4 * k + 0] = v.x; u[4 * k + 1] = v.y;
        u[4 * k + 2] = v.z; u[4 * k + 3] = v.w;
    }
}

// 64-MAC dot, 4 partial accumulators (serial chain 128 -> ~40 cyc).
__device__ __forceinline__ float dot64(const uint32_t* w, const uint32_t* h) {
    float a0 = 0.f, a1 = 0.f, a2 = 0.f, a3 = 0.f;
    #pragma unroll
    for (int k = 0; k < 32; k += 4) {
        a0 = fdot2(w[k + 0], h[k + 0], a0);
        a1 = fdot2(w[k + 1], h[k + 1], a1);
        a2 = fdot2(w[k + 2], h[k + 2], a2);
        a3 = fdot2(w[k + 3], h[k + 3], a3);
    }
    return (a0 + a1) + (a2 + a3);
}

// One 64-float weight row -> 32 packed f16 pairs in VGPRs.
__device__ __forceinline__ void cvt_row(const float* __restrict__ W, int row, uint32_t* dst) {
    const float4* W4 = reinterpret_cast<const float4*>(W + row * HID);
    #pragma unroll
    for (int k = 0; k < 16; ++k) {
        float4 v = W4[k];
        half2_t a{(_Float16)v.x, (_Float16)v.y};
        half2_t b{(_Float16)v.z, (_Float16)v.w};
        dst[2 * k]     = __builtin_bit_cast(uint32_t, a);
        dst[2 * k + 1] = __builtin_bit_cast(uint32_t, b);
    }
}

// One block per batch element; 768 threads = 3 stages x 4 waves.
// Lane map: lane = hloc*4 + cls; wave wv owns h-indices [16wv,16wv+16).
// The 4 gate classes of one h-index live in ONE QUAD -> DPP quad_perm
// broadcast exchange (VALU pipe). All 4 quad lanes redundantly update c
// (consistent), lane cls==0 writes the h-ring. ONE barrier per iteration.
// 5-task wavefront pipeline (R3/R4 schedule):
//   S0: gates0->h0[s]; p1[s-1]=Wih1.h0[s-1]
//   S1: gates1->h1[s-2] (uses p1[s-2]); p2[s-3]=Wih2.h1[s-3]
//   S2: gates2->h2[s-4] (uses p2[s-4])
// p-buffers indexed hidx*4+cls => LDS addr = lane*4 => bank=lane%32, 2-way
// (free; R4's row-major layout was 4-way conflicted). x staged in LDS; the
// loop body has no global memory ops.
__global__ __launch_bounds__(768, 3) void lstm3_fused(
    const float* __restrict__ x,
    const float* __restrict__ Wih0, const float* __restrict__ Whh0,
    const float* __restrict__ bih0, const float* __restrict__ bhh0,
    const float* __restrict__ Wih1, const float* __restrict__ Whh1,
    const float* __restrict__ bih1, const float* __restrict__ bhh1,
    const float* __restrict__ Wih2, const float* __restrict__ Whh2,
    const float* __restrict__ bih2, const float* __restrict__ bhh2,
    const float* __restrict__ fcW,  const float* __restrict__ fcb,
    float* __restrict__ out)
{
    const int b     = blockIdx.x;
    const int tid   = threadIdx.x;
    const int stage = tid >> 8;        // 0,1,2
    const int lane  = tid & 63;
    const int wv    = (tid >> 6) & 3;  // wave within stage
    const int hloc  = lane >> 2;       // 0..15
    const int cls   = lane & 3;        // 0=i,1=f,2=g,3=o (quad-lane index)
    const int hidx  = wv * 16 + hloc;  // h index [0,64)
    const int row   = cls * HID + hidx;// gate row [0,256)
    const int pidx  = hidx * 4 + cls;  // p-buffer slot (lane-linear per wave)

    __shared__ __align__(16) _Float16 h0f[2][HID];
    __shared__ __align__(16) _Float16 h1f[2][HID];
    __shared__ __align__(16) _Float16 h2f[2][HID];
    __shared__ float p1buf[2][NG], p2buf[2][NG];
    __shared__ float hfin[HID];
    __shared__ __align__(16) float xs[T_LEN];

    // Stage x[b,0,:] into LDS (512 float4, coalesced, one pass).
    {
        const float4* xg4 = reinterpret_cast<const float4*>(x + b * T_LEN);
        float4* xs4 = reinterpret_cast<float4*>(xs);
        if (tid < T_LEN / 4) xs4[tid] = xg4[tid];
    }
    if (tid < HID) {
        h0f[0][tid] = (_Float16)0.f; h0f[1][tid] = (_Float16)0.f;
        h1f[0][tid] = (_Float16)0.f; h1f[1][tid] = (_Float16)0.f;
        h2f[0][tid] = (_Float16)0.f; h2f[1][tid] = (_Float16)0.f;
    }

    uint32_t wh[32], wi[32];           // 64 VGPRs of packed f16 weights
    float wx0 = 0.f, bj = 0.f;
    if (stage == 0) {
        wx0 = Wih0[row];               // Wih0 is [256,1]
        bj  = bih0[row] + bhh0[row];
        cvt_row(Whh0, row, wh);
        cvt_row(Wih1, row, wi);        // p1 task
    } else if (stage == 1) {
        bj = bih1[row] + bhh1[row];
        cvt_row(Whh1, row, wh);
        cvt_row(Wih2, row, wi);        // p2 task
    } else {
        bj = bih2[row] + bhh2[row];
        cvt_row(Whh2, row, wh);
        #pragma unroll
        for (int k = 0; k < 32; ++k) wi[k] = 0;
    }

    // Branchless activation: act(x) = sA * rcp(1 + exp2(sE*x)) + sB.
    // cls==2 (g-gate) -> tanh, else sigmoid. log2e folded into sE.
    const bool  isg = (cls == 2);
    const float sE  = isg ? (-2.f * LOG2E) : (-LOG2E);
    const float sA  = isg ?  2.f :  1.f;
    const float sB  = isg ? -1.f :  0.f;

    float c = 0.f;                     // cell state (4 consistent quad copies)
    __syncthreads();

    for (int s = 0; s < NITER; ++s) {
        const int rd = (s + 1) & 1;    // slot written at iter s-1
        const int wr = s & 1;

        bool act;
        float acc;
        uint32_t hv[32];
        if (stage == 0) {
            act = (s < T_LEN);
            load_h(h0f[rd], hv);                       // h0[s-1]
            acc = dot64(wh, hv) + fmaf(wx0, xs[act ? s : 0], bj);
            p1buf[wr][pidx] = dot64(wi, hv);           // p1[s-1] = Wih1.h0[s-1]
        } else if (stage == 1) {
            act = (s >= 2 && s <= T_LEN + 1);
            float p = p1buf[rd][pidx];                 // p1[s-2]
            load_h(h1f[rd], hv);                       // h1[s-3]
            acc = dot64(wh, hv) + (bj + p);
            p2buf[wr][pidx] = dot64(wi, hv);           // p2[s-3] = Wih2.h1[s-3]
        } else {
            act = (s >= 4);
            float p = p2buf[rd][pidx];                 // p2[s-4]
            load_h(h2f[rd], hv);                       // h2[s-5]
            acc = dot64(wh, hv) + (bj + p);
        }

        // Own gate activation (branchless; raw v_exp/v_rcp).
        float a = fmaf(sA, RCPF(1.f + EXP2F(sE * acc)), sB);

        // Quad gate exchange: gate class q sits at quad-lane q.
        float gi = qbcast<0x00>(a);
        float gf = qbcast<0x55>(a);
        float gg = qbcast<0xAA>(a);
        float go = qbcast<0xFF>(a);

        if (act) {
            c = fmaf(gf, c, gi * gg);                  // all 4 quad copies agree
            float tc = fmaf(2.f, RCPF(1.f + EXP2F(-2.f * LOG2E * c)), -1.f);
            float h  = go * tc;
            if (cls == 0) {
                _Float16* ring = (stage == 0) ? h0f[wr]
                               : (stage == 1) ? h1f[wr] : h2f[wr];
                ring[hidx] = (_Float16)h;
                if (stage == 2 && s == NITER - 1) hfin[hidx] = h;  // h2[T-1]
            }
        }
        __syncthreads();   // ring + p-buffer writes visible for iter s+1
    }

    // Final FC (f32): out[b,m] = fcb[m] + fcW[m,:] . h2_last
    if (tid < EMB) {
        float acc = fcb[tid];
        const float4* W4 = reinterpret_cast<const float4*>(fcW + tid * HID);
        const float4* h4 = reinterpret_cast<const float4*>(hfin);
        #pragma unroll
        for (int k = 0; k < 16; ++k) {
            float4 wv4 = W4[k], hv4 = h4[k];
            acc = fmaf(wv4.x, hv4.x, acc);
            acc = fmaf(wv4.y, hv4.y, acc);
            acc = fmaf(wv4.z, hv4.z, acc);
            acc = fmaf(wv4.w, hv4.w, acc);
        }
        out[b * EMB + tid] = acc;
    }
}

extern "C" void kernel_launch(void* const* d_in, const int* in_sizes, int n_in,
                              void* d_out, int out_size, void* d_ws, size_t ws_size,
                              hipStream_t stream) {
    const float* x    = (const float*)d_in[0];
    const float* Wih0 = (const float*)d_in[1];
    const float* Whh0 = (const float*)d_in[2];
    const float* bih0 = (const float*)d_in[3];
    const float* bhh0 = (const float*)d_in[4];
    const float* Wih1 = (const float*)d_in[5];
    const float* Whh1 = (const float*)d_in[6];
    const float* bih1 = (const float*)d_in[7];
    const float* bhh1 = (const float*)d_in[8];
    const float* Wih2 = (const float*)d_in[9];
    const float* Whh2 = (const float*)d_in[10];
    const float* bih2 = (const float*)d_in[11];
    const float* bhh2 = (const float*)d_in[12];
    const float* fcW  = (const float*)d_in[13];
    const float* fcb  = (const float*)d_in[14];
    float* out = (float*)d_out;

    lstm3_fused<<<dim3(256), dim3(768), 0, stream>>>(
        x, Wih0, Whh0, bih0, bhh0,
        Wih1, Whh1, bih1, bhh1,
        Wih2, Whh2, bih2, bhh2,
        fcW, fcb, out);
}